// Round 7
// baseline (94.730 us; speedup 1.0000x reference)
//
#include <hip/hip_runtime.h>
#include <hip/hip_bf16.h>
#include <stdint.h>

#define F_DIM 512
#define H_DIM 256
#define B_DIM 128
#define TEAM_COLS 128
#define NCHUNK 16        // 512 / 32
#define ADEPTH 4         // A register-queue depth (chunks)
#define COL_STRIDE 1040  // 512*2B + 16B pad -> bank-friendly, b128-aligned

typedef __bf16 bf16x8 __attribute__((ext_vector_type(8)));
typedef float  f32x4  __attribute__((ext_vector_type(4)));

// ---- one-time W1 f32 [K=512][C=256] -> bf16 transposed [C=256][K=512] ----
__global__ __launch_bounds__(256) void convert_w1_kernel(
    const float* __restrict__ W1, __bf16* __restrict__ W1t) {
    int t = blockIdx.x * 256 + threadIdx.x;   // t = c*512 + k
    int c = t >> 9;
    int k = t & 511;
    W1t[t] = (__bf16)W1[k * H_DIM + c];
}

// ---- main kernel: persistent blocks, B LDS-resident, barrier-free K-loop ----
// 256 blocks (1/CU, LDS-bound). Team = bid&1 owns a 128-col half of W1t,
// loaded ONCE into LDS. Each of 8 waves independently streams 16-row tiles:
// A held in a depth-4 f32 register queue; per-iteration counted
// `s_waitcnt vmcnt(6)` (memory clobber) pins issue order and keeps 3 chunks
// of HBM lead. A-loads are the ONLY in-loop VMEM -> counts are exact.
__global__ __launch_bounds__(512) void fused_mlp_kernel(
    const float* __restrict__ scaler,
    const __bf16* __restrict__ W1t,
    const float* __restrict__ b1,
    const float* __restrict__ W2,
    float* __restrict__ q_ws,      // [2][N] per-team partial q
    int N, int ntiles)
{
    __shared__ __align__(16) char Bl[TEAM_COLS * COL_STRIDE];   // 130 KB

    const int tid  = threadIdx.x;
    const int lane = tid & 63;
    const int wid  = tid >> 6;          // 0..7
    const int team = blockIdx.x & 1;    // adjacent IDs -> same rows concurrently
    const int idx  = blockIdx.x >> 1;   // 0..127
    const int lrow = lane & 15;
    const int kq   = (lane >> 4) * 8;   // k-elem offset of this lane's fragment

    // ---- fill B LDS once: 128 cols x 512 k bf16, padded col stride ----
    const __bf16* wsrc = W1t + (size_t)team * TEAM_COLS * F_DIM;
    for (int s = tid; s < TEAM_COLS * 64; s += 512) {
        int col = s >> 6, sl = s & 63;
        *(bf16x8*)(Bl + col * COL_STRIDE + sl * 16) =
            *(const bf16x8*)(wsrc + (size_t)col * F_DIM + sl * 8);
    }

    // per-ni constants (loop-invariant): LDS base addr, b1, W2
    int   baddr[8];
    float b1c[8], w2c[8];
    #pragma unroll
    for (int ni = 0; ni < 8; ++ni) {
        int col   = ni * 16 + lrow;
        baddr[ni] = col * COL_STRIDE + kq * 2;
        int gcol  = team * TEAM_COLS + col;
        b1c[ni] = b1[gcol];
        w2c[ni] = W2[gcol];
    }
    asm volatile("s_waitcnt vmcnt(0)" ::: "memory");   // clean vmcnt before loop
    __syncthreads();                                    // B LDS ready (only barrier)

    const int gw = idx * 8 + wid;            // wave id within team [0,1024)
    float* qout = q_ws + (size_t)team * N;

    for (int t = gw; t < ntiles; t += 1024) {
        int row = t * 16 + lrow;
        if (row >= N) row = N - 1;           // clamp loads; stores guarded below
        const float* aptr = scaler + (size_t)row * F_DIM + kq;

        // prologue: fill depth-4 queue (8 loads in flight)
        f32x4 aq[ADEPTH][2];
        #pragma unroll
        for (int d = 0; d < ADEPTH; ++d) {
            aq[d][0] = *(const f32x4*)(aptr + d * 32);
            aq[d][1] = *(const f32x4*)(aptr + d * 32 + 4);
        }

        f32x4 acc[8];
        #pragma unroll
        for (int ni = 0; ni < 8; ++ni) acc[ni] = (f32x4){0.f, 0.f, 0.f, 0.f};

        #pragma unroll
        for (int kc = 0; kc < NCHUNK; ++kc) {
            // counted wait: chunk kc complete; up to 3 chunks stay in flight
            if (kc <= NCHUNK - ADEPTH)  asm volatile("s_waitcnt vmcnt(6)" ::: "memory");
            else if (kc == NCHUNK - 3)  asm volatile("s_waitcnt vmcnt(4)" ::: "memory");
            else if (kc == NCHUNK - 2)  asm volatile("s_waitcnt vmcnt(2)" ::: "memory");
            else                        asm volatile("s_waitcnt vmcnt(0)" ::: "memory");

            const int s = kc % ADEPTH;
            bf16x8 af;
            #pragma unroll
            for (int j = 0; j < 4; ++j) {
                af[j]     = (__bf16)aq[s][0][j];
                af[4 + j] = (__bf16)aq[s][1][j];
            }
            // refill freed slot with chunk kc+4 (pinned between this asm and the next)
            if (kc + ADEPTH < NCHUNK) {
                aq[s][0] = *(const f32x4*)(aptr + (kc + ADEPTH) * 32);
                aq[s][1] = *(const f32x4*)(aptr + (kc + ADEPTH) * 32 + 4);
            }
            // B from LDS (base VGPR + compile-time offset), 8 MFMA
            #pragma unroll
            for (int ni = 0; ni < 8; ++ni) {
                bf16x8 bf = *(const bf16x8*)(Bl + baddr[ni] + kc * 64);
                acc[ni] = __builtin_amdgcn_mfma_f32_16x16x32_bf16(af, bf, acc[ni], 0, 0, 0);
            }
        }

        // ---- epilogue: silu + dot(W2) over this wave's 128 cols ----
        float qp[4] = {0.f, 0.f, 0.f, 0.f};
        #pragma unroll
        for (int ni = 0; ni < 8; ++ni) {
            #pragma unroll
            for (int r = 0; r < 4; ++r) {
                float h  = acc[ni][r] + b1c[ni];
                float sg = h / (1.0f + __expf(-h));
                qp[r] += sg * w2c[ni];
            }
        }
        #pragma unroll
        for (int off = 1; off < 16; off <<= 1)
            #pragma unroll
            for (int r = 0; r < 4; ++r)
                qp[r] += __shfl_xor(qp[r], off, 64);

        if (lrow == 0) {
            #pragma unroll
            for (int r = 0; r < 4; ++r) {
                int grow = t * 16 + (lane >> 4) * 4 + r;
                if (grow < N) qout[grow] = qp[r];
            }
        }
        asm volatile("s_waitcnt vmcnt(0)" ::: "memory");   // drain stores: keep counts exact
    }
}

// ---- finalize: out[b] = sum_i (q0+q1+b2) * ||pos_i - mc[b_i]||^2 ----
__global__ __launch_bounds__(256) void finalize_kernel(
    const float* __restrict__ pos,
    const float* __restrict__ mass_center,
    const int*   __restrict__ batch_index,
    const float* __restrict__ q_ws,
    const float* __restrict__ b2,
    float* __restrict__ out, int N)
{
    __shared__ float pb[B_DIM];
    if (threadIdx.x < B_DIM) pb[threadIdx.x] = 0.f;
    __syncthreads();
    float b2v = b2[0];
    for (int i = blockIdx.x * 256 + threadIdx.x; i < N; i += gridDim.x * 256) {
        float q  = q_ws[i] + q_ws[N + i] + b2v;
        int   bi = batch_index[i];
        float dx = pos[i * 3 + 0] - mass_center[bi * 3 + 0];
        float dy = pos[i * 3 + 1] - mass_center[bi * 3 + 1];
        float dz = pos[i * 3 + 2] - mass_center[bi * 3 + 2];
        atomicAdd(&pb[bi], q * (dx * dx + dy * dy + dz * dz));
    }
    __syncthreads();
    if (threadIdx.x < B_DIM) atomicAdd(&out[threadIdx.x], pb[threadIdx.x]);
}

extern "C" void kernel_launch(void* const* d_in, const int* in_sizes, int n_in,
                              void* d_out, int out_size, void* d_ws, size_t ws_size,
                              hipStream_t stream) {
    const float* pos         = (const float*)d_in[0];
    const float* mass_center = (const float*)d_in[1];
    const float* scaler      = (const float*)d_in[2];
    // d_in[3] = vector : unused by the reference computation
    const int*   batch_index = (const int*)d_in[4];
    const float* W1          = (const float*)d_in[5];
    const float* b1          = (const float*)d_in[6];
    const float* W2          = (const float*)d_in[7];
    const float* b2          = (const float*)d_in[8];
    float* out = (float*)d_out;
    (void)n_in; (void)out_size; (void)ws_size;

    int N      = in_sizes[0] / 3;
    int ntiles = (N + 15) / 16;

    __bf16* W1t  = (__bf16*)d_ws;                                  // 256 KB
    float*  q_ws = (float*)((char*)d_ws + (size_t)F_DIM * H_DIM * 2); // 2*N f32

    hipMemsetAsync(out, 0, B_DIM * sizeof(float), stream);
    convert_w1_kernel<<<(F_DIM * H_DIM) / 256, 256, 0, stream>>>(W1, W1t);
    fused_mlp_kernel<<<256, 512, 0, stream>>>(scaler, W1t, b1, W2, q_ws, N, ntiles);
    finalize_kernel<<<128, 256, 0, stream>>>(pos, mass_center, batch_index,
                                             q_ws, b2, out, N);
}

// Round 8
// 78.127 us; speedup vs baseline: 1.2125x; 1.2125x over previous
//
#include <hip/hip_runtime.h>
#include <hip/hip_bf16.h>
#include <stdint.h>

#define F_DIM 512
#define H_DIM 256
#define B_DIM 128
#define M_BLK 64
#define NCHUNK 16   // 512 / 32
#define NBUF 2

typedef __bf16 bf16x8 __attribute__((ext_vector_type(8)));
typedef float  f32x4  __attribute__((ext_vector_type(4)));

// ---- one-time W1 f32 [K=512][C=256] -> bf16 transposed [C=256][K=512] ----
__global__ __launch_bounds__(256) void convert_w1_kernel(
    const float* __restrict__ W1, __bf16* __restrict__ W1t) {
    int t = blockIdx.x * 256 + threadIdx.x;   // t = c*512 + k
    int c = t >> 9;
    int k = t & 511;
    W1t[t] = (__bf16)W1[k * H_DIM + c];
}

__device__ inline void gload_lds16(const float* g, float* lds) {
    __builtin_amdgcn_global_load_lds(
        (const __attribute__((address_space(1))) uint32_t*)g,
        (__attribute__((address_space(3))) uint32_t*)lds, 16, 0, 0);
}
__device__ inline void gload_lds16b(const __bf16* g, __bf16* lds) {
    __builtin_amdgcn_global_load_lds(
        (const __attribute__((address_space(1))) uint32_t*)g,
        (__attribute__((address_space(3))) uint32_t*)lds, 16, 0, 0);
}

// B seg swizzle: 2-way-max bank pattern for the [col][64B] layout
__device__ inline int bswz(int col) { return (col & 3) ^ ((col >> 2) & 3); }

// ---- main fused kernel: R6 structure + B-swizzle + NBUF=2 (3 blocks/CU) ----
template<bool USE_PARTIAL>
__global__ __launch_bounds__(512, 6) void fused_mlp_kernel(
    const float* __restrict__ pos,
    const float* __restrict__ mass_center,
    const float* __restrict__ scaler,
    const int*   __restrict__ batch_index,
    const __bf16* __restrict__ W1t,
    const float* __restrict__ b1,
    const float* __restrict__ W2,
    const float* __restrict__ b2,
    float* __restrict__ outp,
    int N)
{
    __shared__ float  A_lds[NBUF][M_BLK][32];    // 2 x 8 KB
    __shared__ __bf16 Bc_lds[NBUF][H_DIM][32];   // 2 x 16 KB
    __shared__ float  q_lds[M_BLK];
    __shared__ float  pb[B_DIM];

    const int tid    = threadIdx.x;
    const int lane   = tid & 63;
    const int wid    = tid >> 6;     // 0..7
    const int wave_m = wid >> 2;     // 0..1 -> 32-row strip
    const int wave_n = wid & 3;      // 0..3 -> 64-col strip
    const int lrow   = lane & 15;
    const int kq     = (lane >> 4) * 8;   // k-elem offset of this lane's fragment
    const int row_base = blockIdx.x * M_BLK;

    if (tid < M_BLK) q_lds[tid] = 0.f;
    if (USE_PARTIAL && tid < B_DIM) pb[tid] = 0.f;

    // -- A staging: slot t -> row t>>3, phys 16B seg t&7; source seg XOR'd by
    //    row&7 (linear LDS dest + pre-swizzled source; read XOR-unswizzles).
    const int srow = tid >> 3;
    const int sseg = (tid & 7) ^ (srow & 7);
    int grA = row_base + srow; if (grA >= N) grA = N - 1;
    const float* gsA = scaler + (size_t)grA * F_DIM + sseg * 4;

    // -- B staging: pass p slot s=p*512+tid -> col s>>2, phys seg s&3;
    //    source seg = (s&3) ^ bswz(col).
    const int c0 = tid >> 2,         g0 = (tid & 3) ^ bswz(c0);
    const int c1 = (512 + tid) >> 2, g1 = ((512 + tid) & 3) ^ bswz(c1);
    const __bf16* gsB0 = W1t + (size_t)c0 * F_DIM + g0 * 8;
    const __bf16* gsB1 = W1t + (size_t)c1 * F_DIM + g1 * 8;

#define STAGE(buf, c) do {                                                      \
        gload_lds16 (gsA  + (c) * 32, &A_lds[(buf)][0][0] + wid * 256);         \
        gload_lds16b(gsB0 + (c) * 32, &Bc_lds[(buf)][0][0] + wid * 512);        \
        gload_lds16b(gsB1 + (c) * 32, &Bc_lds[(buf)][0][0] + 4096 + wid * 512); \
    } while (0)

    f32x4 acc[2][4];
    #pragma unroll
    for (int mi = 0; mi < 2; ++mi)
        #pragma unroll
        for (int ni = 0; ni < 4; ++ni)
            acc[mi][ni] = (f32x4){0.f, 0.f, 0.f, 0.f};

    // prologue: 2 chunks in flight (6 VMEM/thread)
    STAGE(0, 0);
    STAGE(1, 1);

    #pragma unroll
    for (int kc = 0; kc < NCHUNK; ++kc) {
        // counted wait: stage(kc) complete; stage(kc+1) stays in flight
        if (kc < NCHUNK - 1) asm volatile("s_waitcnt vmcnt(3)" ::: "memory");
        else                 asm volatile("s_waitcnt vmcnt(0)" ::: "memory");
        __builtin_amdgcn_s_barrier();

        // ---- compute chunk kc from buf kc&1 (all operands from LDS) ----
        const int buf = kc & 1;
        bf16x8 af[2];
        #pragma unroll
        for (int mi = 0; mi < 2; ++mi) {
            const int rA = wave_m * 32 + mi * 16 + lrow;
            const int sw = (rA & 7) << 4;
            const char* rb = (const char*)&A_lds[buf][0][0] + rA * 128;
            f32x4 a0 = *(const f32x4*)(rb + ((kq * 4) ^ sw));
            f32x4 a1 = *(const f32x4*)(rb + ((kq * 4 + 16) ^ sw));
            #pragma unroll
            for (int j = 0; j < 4; ++j) {
                af[mi][j]     = (__bf16)a0[j];
                af[mi][4 + j] = (__bf16)a1[j];
            }
        }
        bf16x8 bfrag[4];
        #pragma unroll
        for (int ni = 0; ni < 4; ++ni) {
            const int col = wave_n * 64 + ni * 16 + lrow;
            const int ps  = (lane >> 4) ^ bswz(col);   // physical 16B seg
            bfrag[ni] = *(const bf16x8*)((const char*)&Bc_lds[buf][0][0]
                                         + col * 64 + ps * 16);
        }
        #pragma unroll
        for (int mi = 0; mi < 2; ++mi)
            #pragma unroll
            for (int ni = 0; ni < 4; ++ni)
                acc[mi][ni] = __builtin_amdgcn_mfma_f32_16x16x32_bf16(
                    af[mi], bfrag[ni], acc[mi][ni], 0, 0, 0);

        __builtin_amdgcn_s_barrier();   // all readers done with buf kc&1
        if (kc + 2 < NCHUNK)
            STAGE(buf, kc + 2);         // refill the buffer just vacated
    }
#undef STAGE

    // ---- epilogue: silu + dot(W2), reduce over the 16 col-lanes ----
    float qp[2][4];
    #pragma unroll
    for (int mi = 0; mi < 2; ++mi)
        #pragma unroll
        for (int r = 0; r < 4; ++r) qp[mi][r] = 0.f;

    #pragma unroll
    for (int ni = 0; ni < 4; ++ni) {
        int c = wave_n * 64 + ni * 16 + lrow;
        float b1c = b1[c];
        float w2c = W2[c];
        #pragma unroll
        for (int mi = 0; mi < 2; ++mi)
            #pragma unroll
            for (int r = 0; r < 4; ++r) {
                float h = acc[mi][ni][r] + b1c;
                float s = h / (1.0f + __expf(-h));
                qp[mi][r] += s * w2c;
            }
    }
    #pragma unroll
    for (int off = 1; off < 16; off <<= 1)
        #pragma unroll
        for (int mi = 0; mi < 2; ++mi)
            #pragma unroll
            for (int r = 0; r < 4; ++r)
                qp[mi][r] += __shfl_xor(qp[mi][r], off, 64);

    if ((lane & 15) == 0) {
        int rgrp = lane >> 4;
        #pragma unroll
        for (int mi = 0; mi < 2; ++mi)
            #pragma unroll
            for (int r = 0; r < 4; ++r)
                atomicAdd(&q_lds[wave_m * 32 + mi * 16 + rgrp * 4 + r], qp[mi][r]);
    }
    __syncthreads();

    if (tid < M_BLK) {
        int grow = row_base + tid;
        if (grow < N) {
            float q  = q_lds[tid] + b2[0];
            int   bi = batch_index[grow];
            float dx = pos[grow * 3 + 0] - mass_center[bi * 3 + 0];
            float dy = pos[grow * 3 + 1] - mass_center[bi * 3 + 1];
            float dz = pos[grow * 3 + 2] - mass_center[bi * 3 + 2];
            float val = q * (dx * dx + dy * dy + dz * dz);
            if (USE_PARTIAL) atomicAdd(&pb[bi], val);
            else             atomicAdd(&outp[bi], val);
        }
    }
    if (USE_PARTIAL) {
        __syncthreads();
        if (tid < B_DIM)
            outp[(size_t)blockIdx.x * B_DIM + tid] = pb[tid];
    }
}

// ---- reduce per-block partials [nblk][128] -> out[128] ----
__global__ __launch_bounds__(256) void reduce_partials_kernel(
    const float* __restrict__ partial, float* __restrict__ out, int nblk) {
    int b = blockIdx.x;
    float s = 0.f;
    for (int i = threadIdx.x; i < nblk; i += 256)
        s += partial[(size_t)i * B_DIM + b];
    #pragma unroll
    for (int off = 1; off < 64; off <<= 1)
        s += __shfl_xor(s, off, 64);
    __shared__ float wsum[4];
    if ((threadIdx.x & 63) == 0) wsum[threadIdx.x >> 6] = s;
    __syncthreads();
    if (threadIdx.x == 0)
        out[b] = wsum[0] + wsum[1] + wsum[2] + wsum[3];
}

extern "C" void kernel_launch(void* const* d_in, const int* in_sizes, int n_in,
                              void* d_out, int out_size, void* d_ws, size_t ws_size,
                              hipStream_t stream) {
    const float* pos         = (const float*)d_in[0];
    const float* mass_center = (const float*)d_in[1];
    const float* scaler      = (const float*)d_in[2];
    // d_in[3] = vector : unused by the reference computation
    const int*   batch_index = (const int*)d_in[4];
    const float* W1          = (const float*)d_in[5];
    const float* b1          = (const float*)d_in[6];
    const float* W2          = (const float*)d_in[7];
    const float* b2          = (const float*)d_in[8];
    float* out = (float*)d_out;
    (void)n_in; (void)out_size;

    int N = in_sizes[0] / 3;
    int nblk = (N + M_BLK - 1) / M_BLK;

    size_t w1t_bytes  = (size_t)F_DIM * H_DIM * sizeof(__bf16);   // 256 KB
    size_t part_bytes = (size_t)nblk * B_DIM * sizeof(float);

    __bf16* W1t = (__bf16*)d_ws;
    convert_w1_kernel<<<(F_DIM * H_DIM) / 256, 256, 0, stream>>>(W1, W1t);

    if (ws_size >= w1t_bytes + part_bytes) {
        float* partial = (float*)((char*)d_ws + w1t_bytes);
        fused_mlp_kernel<true><<<nblk, 512, 0, stream>>>(
            pos, mass_center, scaler, batch_index, W1t, b1, W2, b2, partial, N);
        reduce_partials_kernel<<<B_DIM, 256, 0, stream>>>(partial, out, nblk);
    } else {
        hipMemsetAsync(out, 0, B_DIM * sizeof(float), stream);
        fused_mlp_kernel<false><<<nblk, 512, 0, stream>>>(
            pos, mass_center, scaler, batch_index, W1t, b1, W2, b2, out, N);
    }
}